// Round 5
// baseline (267.660 us; speedup 1.0000x reference)
//
#include <hip/hip_runtime.h>
#include <cfloat>
#include <math.h>

#define NB 8
#define NPT 4096
#define NC 64
#define KNN 20
#define KSZ 16
#define BPTS 16

typedef __attribute__((ext_vector_type(8))) short short8;
typedef __attribute__((ext_vector_type(4))) float f32x4;

// ---------- helpers ----------
__device__ __forceinline__ unsigned short f2bf(float f) {
  unsigned u = __float_as_uint(f);
  unsigned r = (u + 0x7fffu + ((u >> 16) & 1u)) >> 16;
  return (unsigned short)r;
}
__device__ __forceinline__ float bf2f(unsigned short h) {
  return __uint_as_float(((unsigned)h) << 16);
}

// ---------- K0a: conv_w [64][2048] -> Bpack bf16 in MFMA B-frag order ----------
__global__ void k_pack_cw(const float* __restrict__ cw, unsigned short* __restrict__ bp) {
  int t = blockIdx.x * 256 + threadIdx.x;  // 131072
  int j = t & 7, lane = (t >> 3) & 63, nt = (t >> 9) & 3, ks = t >> 11;
  int k = ks * 32 + ((lane >> 4) << 3) + j;
  int o = nt * 16 + (lane & 15);
  bp[t] = f2bf(cw[o * 2048 + k]);
}

// ---------- K0b: feature [B][C][N] -> ftT [B][N][C] bf16 ----------
__global__ void k_transpose_ft(const float* __restrict__ f, unsigned short* __restrict__ ft) {
  __shared__ float tile[64][65];
  int b = blockIdx.x >> 6;
  int n0 = (blockIdx.x & 63) * 64;
  int lane = threadIdx.x & 63;
  int rr = threadIdx.x >> 6;  // 0..3
#pragma unroll
  for (int c0 = 0; c0 < 64; c0 += 4) {
    int c = c0 + rr;
    tile[c][lane] = f[(b * 64 + c) * 4096 + n0 + lane];
  }
  __syncthreads();
#pragma unroll
  for (int m0 = 0; m0 < 64; m0 += 4) {
    int nn = m0 + rr;
    ft[(b * 4096 + n0 + nn) * 64 + lane] = f2bf(tile[lane][nn]);
  }
}

// ---------- K1: KNN v3 (unchanged from R4) ----------
__device__ __noinline__ void knn_full(const float4* __restrict__ pts, int n, int lane,
                                      int g, int* __restrict__ idxOut) {
  const int M = 24;
  float4 qp = pts[n];
  float qx = qp.x, qy = qp.y, qz = qp.z;
  float v[M];
  int id[M];
#pragma unroll
  for (int r = 0; r < M; ++r) { v[r] = FLT_MAX; id[r] = 0x7fffffff; }
  for (int i = 0; i < 64; ++i) {
    int j = (i << 6) | lane;
    float4 p = pts[j];
    float dx = p.x - qx, dy = p.y - qy, dz = p.z - qz;
    float d2 = fmaf(dx, dx, fmaf(dy, dy, dz * dz));
    bool c[M];
#pragma unroll
    for (int r = 0; r < M; ++r) c[r] = d2 < v[r];
#pragma unroll
    for (int r = M - 1; r >= 1; --r) {
      v[r] = c[r - 1] ? v[r - 1] : (c[r] ? d2 : v[r]);
      id[r] = c[r - 1] ? id[r - 1] : (c[r] ? j : id[r]);
    }
    v[0] = c[0] ? d2 : v[0];
    id[0] = c[0] ? j : id[0];
  }
  unsigned long long key = ((unsigned long long)__float_as_uint(v[0]) << 32) | (unsigned)id[0];
  unsigned long long ext = ~0ull;
  for (int r = 0; r < 24; ++r) {
    unsigned long long k = key;
#pragma unroll
    for (int s = 1; s < 64; s <<= 1) {
      unsigned long long o = __shfl_xor(k, s, 64);
      k = (o < k) ? o : k;
    }
    if (lane == r) ext = k;
    if (key == k) {
#pragma unroll
      for (int q = 0; q < M - 1; ++q) { v[q] = v[q + 1]; id[q] = id[q + 1]; }
      v[M - 1] = FLT_MAX;
      id[M - 1] = 0x7fffffff;
      key = ((unsigned long long)__float_as_uint(v[0]) << 32) | (unsigned)id[0];
    }
  }
  int ei = (int)(unsigned)(ext & 0xffffffffu);
  bool al = lane < 24;
  double dv = -1.0;
  if (al) {
    float4 p = pts[ei];
    double dx = (double)p.x - (double)qx;
    double dy = (double)p.y - (double)qy;
    double dz = (double)p.z - (double)qz;
    dv = dx * dx + dy * dy + dz * dz;
  }
#pragma unroll
  for (int r = 0; r < 4; ++r) {
    double bd = al ? dv : -1.0;
    int bi = al ? ei : -1;
#pragma unroll
    for (int s = 1; s < 64; s <<= 1) {
      double od = __shfl_xor(bd, s, 64);
      int oi = __shfl_xor(bi, s, 64);
      if (od > bd || (od == bd && oi > bi)) { bd = od; bi = oi; }
    }
    if (al && ei == bi) al = false;
  }
  unsigned long long msk = __ballot(al && ei != n);
  if (al) {
    if (ei == n) {
      idxOut[g * 20] = n;
    } else {
      int pos = 1 + __popcll(msk & ((1ull << lane) - 1ull));
      idxOut[g * 20 + pos] = ei;
    }
  }
}

__launch_bounds__(1024, 8)
__global__ void k_knn(const float* __restrict__ x, int* __restrict__ idxOut) {
  __shared__ float4 pts[4096];  // 64KB: (x,y,z,xx)
  int b = blockIdx.x >> 8;
  const float* xb = x + b * 3 * 4096;
  for (int i = threadIdx.x; i < 4096; i += 1024) {
    float px = xb[i], py = xb[4096 + i], pz = xb[8192 + i];
    pts[i] = make_float4(px, py, pz, fmaf(px, px, fmaf(py, py, pz * pz)));
  }
  __syncthreads();

  int lane = threadIdx.x & 63;
  int n = ((blockIdx.x & 255) << 4) + (threadIdx.x >> 6);
  int g = b * 4096 + n;

  float4 qp = pts[n];
  float m2x = -2.0f * qp.x, m2y = -2.0f * qp.y, m2z = -2.0f * qp.z;

  // ---- pass 1: per-lane min ----
  float v = FLT_MAX;
#pragma unroll 4
  for (int i = 0; i < 64; ++i) {
    float4 p = pts[(i << 6) | lane];
    float d = fmaf(m2z, p.z, fmaf(m2y, p.y, fmaf(m2x, p.x, p.w)));
    v = fminf(v, d);
  }

  // ---- bitonic sort 64 lane minima (ascending by lane) ----
#pragma unroll
  for (int k = 2; k <= 64; k <<= 1) {
#pragma unroll
    for (int j = k >> 1; j > 0; j >>= 1) {
      float o = __shfl_xor(v, j, 64);
      bool up = ((lane & k) == 0);
      bool lower = ((lane & j) == 0);
      float mn = fminf(v, o), mx = fmaxf(v, o);
      v = (up == lower) ? mn : mx;
    }
  }
  float T = __shfl(v, 23, 64);  // >= f32 rank-24 of the full row

  // ---- pass 2: collect all d' <= T, compact via ds_permute ----
  int ei = -1;
  int base = 0;
  bool ovf = false;
#pragma unroll 2
  for (int i = 0; i < 64; ++i) {
    int j = (i << 6) | lane;
    float4 p = pts[j];
    float d = fmaf(m2z, p.z, fmaf(m2y, p.y, fmaf(m2x, p.x, p.w)));
    bool pred = (d <= T);
    unsigned long long mask = __ballot(pred);
    if (mask) {
      int cnt = __popcll(mask);
      if (base + cnt > 63) {
        ovf = true;
      } else {
        int dst = pred ? (base + __popcll(mask & ((1ull << lane) - 1ull))) : 63;
        int got = __builtin_amdgcn_ds_permute(dst << 2, j);
        bool recv = (lane >= base) && (lane < base + cnt);
        ei = recv ? got : ei;
      }
      base += cnt;
    }
  }

  bool ok = !ovf;
  if (ok) {
    // ---- exact f64 lex rank-by-count over the |S|=base candidates ----
    bool act = lane < base;
    double dm = 1e300;
    if (act) {
      float4 p = pts[ei];
      double dx = (double)p.x - (double)qp.x;
      double dy = (double)p.y - (double)qp.y;
      double dz = (double)p.z - (double)qp.z;
      dm = dx * dx + dy * dy + dz * dz;
    }
    int rank = 0;
    for (int r = 0; r < base; ++r) {
      double dr = __shfl(dm, r, 64);
      int ir = __shfl(ei, r, 64);
      bool less = (dr < dm) || (dr == dm && ir < ei);
      rank += less ? 1 : 0;
    }
    bool keep = act && (rank < 20);
    bool isSelf = keep && (ei == n);
    unsigned long long smask = __ballot(isSelf);
    ok = (smask != 0ull);
    if (ok) {
      if (isSelf) idxOut[g * 20] = n;
      unsigned long long msk = __ballot(keep && !isSelf);
      if (keep && !isSelf) {
        int pos = 1 + __popcll(msk & ((1ull << lane) - 1ull));
        idxOut[g * 20 + pos] = ei;
      }
    }
  }
  if (!ok) knn_full(pts, n, lane, g, idxOut);
}

// ---------- K2: fused features + aw + agg(bf16,swizzled) + MFMA conv ----------
__device__ __forceinline__ void mfma_pass(const unsigned short* aggp,
                                          const unsigned short* __restrict__ bp,
                                          int t, int lane, int ksbase, f32x4 acc[4]) {
  int w = t >> 6;
  int r = lane & 15;
  const char* rowbase = (const char*)aggp + r * 2048;
#pragma unroll
  for (int ks = 0; ks < 4; ++ks) {
    int ksl = w * 4 + ks;
    int off = (ksl * 64 + ((lane >> 4) << 4)) ^ ((r & 7) << 4);
    short8 af = *(const short8*)(rowbase + off);
#pragma unroll
    for (int nt = 0; nt < 4; ++nt) {
      int ksg = ksbase + ksl;
      short8 bf = *(const short8*)(bp + (((ksg * 4 + nt) * 64 + lane) << 3));
      acc[nt] = __builtin_amdgcn_mfma_f32_16x16x32_bf16(af, bf, acc[nt], 0, 0, 0);
    }
  }
}

// 2 blocks/CU is the LDS cap (62KB/block); ask only for that -> VGPR cap 128, no spills.
__launch_bounds__(512, 2)
__global__ void k_main(const float* __restrict__ x, const float* __restrict__ feat,
                       const unsigned short* __restrict__ ftT, int useFtT,
                       const float* __restrict__ kern, const float* __restrict__ mlp_w,
                       const float* __restrict__ mlp_b, const unsigned short* __restrict__ bp,
                       const float* __restrict__ conv_b, const int* __restrict__ idxIn,
                       float* __restrict__ out) {
  __shared__ __align__(16) unsigned short agg[BPTS][1024];  // 32KB swizzled bf16; reused as f32 red
  __shared__ float awL[BPTS][20][16];                       // 20.5KB
  __shared__ float f7L[BPTS][20][7];                        // 9KB
  __shared__ int idxL[BPTS][20];

  int t = threadIdx.x;
  int lane = t & 63;
  // XCD-aware swizzle: workgroups round-robin over the 8 XCDs, so batch = blockIdx&7
  // pins each batch's 512KB ftT slice (+256KB weights) into ONE XCD's private L2.
  int b = blockIdx.x & 7;
  int n0 = (blockIdx.x >> 3) * BPTS;
  int g0 = b * 4096 + n0;
  const float* xb = x + b * 3 * 4096;

  // ---- step 0: per-neighbor geometry + raw aw (16 pts x 20 nbrs on 512 thr) ----
  {
    int pt = t >> 5, slot = t & 31;
    if (slot < 20) {
      int n = n0 + pt;
      int kk = idxIn[(g0 + pt) * 20 + slot];
      idxL[pt][slot] = kk;
      float qx = xb[n], qy = xb[4096 + n], qz = xb[8192 + n];
      float rx = xb[kk] - qx, ry = xb[4096 + kk] - qy, rz = xb[8192 + kk] - qz;
      float ds = sqrtf(rx * rx + ry * ry + rz * rz);
      f7L[pt][slot][0] = qx;
      f7L[pt][slot][1] = qy;
      f7L[pt][slot][2] = qz;
      f7L[pt][slot][3] = rx;
      f7L[pt][slot][4] = ry;
      f7L[pt][slot][5] = rz;
      f7L[pt][slot][6] = ds;
#pragma unroll
      for (int s = 0; s < 16; ++s) {
        float dot = rx * kern[s] + ry * kern[16 + s] + rz * kern[32 + s];
        if (slot == 0 && s == 0) dot += 1.0f;
        awL[pt][slot][s] = dot > 0.0f ? dot : 0.0f;
      }
    }
  }
  __syncthreads();

  // ---- step 1: aw normalization chain (256 thr: one per (pt,s)) ----
  if (t < 256) {
    int pp = t >> 4, s = t & 15;
    float sum = 0.0f;
#pragma unroll
    for (int k = 0; k < 20; ++k) sum += awL[pp][k][s];
    float inv1 = 1.0f / (sum + 1e-6f);
    float sum2 = 0.0f;
#pragma unroll
    for (int k = 0; k < 20; ++k) {
      float w = awL[pp][k][s] * inv1;
      sum2 += w * w;
    }
    float inv2 = 1.0f / (sum2 + 1e-6f);
#pragma unroll
    for (int k = 0; k < 20; ++k) {
      float w = awL[pp][k][s] * inv1;
      w = w * w * inv2;
      awL[pp][k][s] = (w > 0.1f) ? w : 0.0f;
    }
  }
  __syncthreads();

  f32x4 acc[4];
#pragma unroll
  for (int nt = 0; nt < 4; ++nt) acc[nt] = (f32x4){0.f, 0.f, 0.f, 0.f};
  int c = lane;

  // ---- phase A1: spiral half (K = 0..1023) ----
#pragma unroll
  for (int half = 0; half < 2; ++half) {
    int pt = ((t >> 6) << 1) + half;
    float fv[20];
    if (useFtT) {
#pragma unroll
      for (int k = 0; k < 20; ++k) fv[k] = bf2f(ftT[(b * 4096 + idxL[pt][k]) * 64 + c]);
    } else {
      const float* fb = feat + (b * 64 + c) * 4096;
#pragma unroll
      for (int k = 0; k < 20; ++k) fv[k] = fb[idxL[pt][k]];
    }
    float a1[16];
#pragma unroll
    for (int s = 0; s < 16; ++s) a1[s] = 0.0f;
#pragma unroll
    for (int k = 0; k < 20; ++k) {
      float a = fv[k];
#pragma unroll
      for (int s = 0; s < 16; ++s) a1[s] = fmaf(a, awL[pt][k][s], a1[s]);
    }
    __align__(16) unsigned short tmp[16];
#pragma unroll
    for (int s = 0; s < 16; ++s) tmp[s] = f2bf(a1[s]);
    char* rb = (char*)&agg[pt][0];
    int sw = (pt & 7) << 4;
    *(uint4*)(rb + ((c * 32) ^ sw)) = *(uint4*)&tmp[0];
    *(uint4*)(rb + ((c * 32 + 16) ^ sw)) = *(uint4*)&tmp[8];
  }
  __syncthreads();
  mfma_pass(&agg[0][0], bp, t, lane, 0, acc);
  __syncthreads();

  // ---- phase A2: x_feats half (K = 1024..2047) ----
#pragma unroll
  for (int half = 0; half < 2; ++half) {
    int pt = ((t >> 6) << 1) + half;
    float mw[7];
#pragma unroll
    for (int j = 0; j < 7; ++j) mw[j] = mlp_w[c * 7 + j];
    float mb = mlp_b[c];
    float xf[20];
#pragma unroll
    for (int k = 0; k < 20; ++k) {
      float s = mb;
#pragma unroll
      for (int j = 0; j < 7; ++j) s = fmaf(mw[j], f7L[pt][k][j], s);
      xf[k] = s;
    }
    float a1[16];
#pragma unroll
    for (int s = 0; s < 16; ++s) a1[s] = 0.0f;
#pragma unroll
    for (int k = 0; k < 20; ++k) {
      float a = xf[k];
#pragma unroll
      for (int s = 0; s < 16; ++s) a1[s] = fmaf(a, awL[pt][k][s], a1[s]);
    }
    __align__(16) unsigned short tmp[16];
#pragma unroll
    for (int s = 0; s < 16; ++s) tmp[s] = f2bf(a1[s]);
    char* rb = (char*)&agg[pt][0];
    int sw = (pt & 7) << 4;
    *(uint4*)(rb + ((c * 32) ^ sw)) = *(uint4*)&tmp[0];
    *(uint4*)(rb + ((c * 32 + 16) ^ sw)) = *(uint4*)&tmp[8];
  }
  __syncthreads();
  mfma_pass(&agg[0][0], bp, t, lane, 32, acc);
  __syncthreads();  // before reusing agg as red

  // ---- cross-wave reduce ----
  float* red = (float*)&agg[0][0];  // 32KB
  {
    int w = t >> 6;
#pragma unroll
    for (int nt = 0; nt < 4; ++nt)
#pragma unroll
      for (int r = 0; r < 4; ++r) {
        int pt = ((lane >> 4) << 2) + r;
        int o = nt * 16 + (lane & 15);
        red[(w * 16 + pt) * 64 + (o ^ ((pt & 7) << 2))] = acc[nt][r];
      }
  }
  __syncthreads();
#pragma unroll
  for (int rep = 0; rep < 2; ++rep) {
    int u = rep * 512 + t;
    int pt = u & 15, o = u >> 4;
    float s = conv_b[o];
#pragma unroll
    for (int w = 0; w < 8; ++w) s += red[(w * 16 + pt) * 64 + (o ^ ((pt & 7) << 2))];
    out[(b * 64 + o) * 4096 + n0 + pt] = s;
  }
}

// ---------- K3a: BN stats ----------
__global__ void k_bnstats(const float* __restrict__ out, const float* __restrict__ gamma,
                          const float* __restrict__ beta, float* __restrict__ stats) {
  __shared__ double rs[256], rq[256];
  int o = blockIdx.x;
  double s = 0.0, q = 0.0;
  for (int b = 0; b < 8; ++b) {
    const float* p = out + (b * 64 + o) * 4096;
    for (int i = threadIdx.x; i < 4096; i += 256) {
      double v = (double)p[i];
      s += v;
      q += v * v;
    }
  }
  rs[threadIdx.x] = s;
  rq[threadIdx.x] = q;
  __syncthreads();
  for (int st = 128; st > 0; st >>= 1) {
    if ((int)threadIdx.x < st) {
      rs[threadIdx.x] += rs[threadIdx.x + st];
      rq[threadIdx.x] += rq[threadIdx.x + st];
    }
    __syncthreads();
  }
  if (threadIdx.x == 0) {
    double mean = rs[0] / 32768.0;
    double var = rq[0] / 32768.0 - mean * mean;
    double inv = 1.0 / sqrt(var + 1e-5);
    double sc = (double)gamma[o] * inv;
    stats[o * 2] = (float)sc;
    stats[o * 2 + 1] = (float)((double)beta[o] - mean * sc);
  }
}

// ---------- K3b: BN apply ----------
__global__ void k_bnapply(float* __restrict__ out, const float* __restrict__ stats) {
  int i = blockIdx.x * 256 + threadIdx.x;
  int o = (i >> 12) & 63;
  out[i] = fmaf(out[i], stats[o * 2], stats[o * 2 + 1]);
}

extern "C" void kernel_launch(void* const* d_in, const int* in_sizes, int n_in,
                              void* d_out, int out_size, void* d_ws, size_t ws_size,
                              hipStream_t stream) {
  const float* x = (const float*)d_in[0];
  const float* feat = (const float*)d_in[1];
  const float* kern = (const float*)d_in[2];
  const float* mlp_w = (const float*)d_in[3];
  const float* mlp_b = (const float*)d_in[4];
  const float* conv_w = (const float*)d_in[5];
  const float* conv_b = (const float*)d_in[6];
  const float* gamma = (const float*)d_in[7];
  const float* beta = (const float*)d_in[8];
  float* out = (float*)d_out;
  char* ws = (char*)d_ws;

  // workspace layout
  int* idx = (int*)ws;                                   // 2,621,440 B
  float* stats = (float*)(ws + 2621440);                 // 4 KB pad
  unsigned short* bpk = (unsigned short*)(ws + 2625536); // 262,144 B
  unsigned short* ftT = (unsigned short*)(ws + 2887680); // 4,194,304 B
  int useFtT = (ws_size >= (size_t)(2887680 + 4194304)) ? 1 : 0;

  k_pack_cw<<<512, 256, 0, stream>>>(conv_w, bpk);
  if (useFtT) k_transpose_ft<<<512, 256, 0, stream>>>(feat, ftT);
  k_knn<<<2048, 1024, 0, stream>>>(x, idx);
  k_main<<<2048, 512, 0, stream>>>(x, feat, ftT, useFtT, kern, mlp_w, mlp_b, bpk,
                                   conv_b, idx, out);
  k_bnstats<<<64, 256, 0, stream>>>(out, gamma, beta, stats);
  k_bnapply<<<8192, 256, 0, stream>>>(out, stats);
}

// Round 6
// 210.465 us; speedup vs baseline: 1.2718x; 1.2718x over previous
//
#include <hip/hip_runtime.h>
#include <cfloat>
#include <math.h>

#define NB 8
#define NPT 4096
#define NC 64
#define KNN 20
#define KSZ 16
#define BPTS 8

typedef __attribute__((ext_vector_type(8))) short short8;
typedef __attribute__((ext_vector_type(4))) float f32x4;

// ---------- helpers ----------
__device__ __forceinline__ unsigned short f2bf(float f) {
  unsigned u = __float_as_uint(f);
  unsigned r = (u + 0x7fffu + ((u >> 16) & 1u)) >> 16;
  return (unsigned short)r;
}
__device__ __forceinline__ float bf2f(unsigned short h) {
  return __uint_as_float(((unsigned)h) << 16);
}

// ---------- K0a: conv_w lower half [64][0..1023] -> bpk B-frag bf16 (K=1024) ----------
__global__ void k_pack_cw(const float* __restrict__ cw, unsigned short* __restrict__ bp) {
  int t = blockIdx.x * 256 + threadIdx.x;  // 65536
  int j = t & 7, lane = (t >> 3) & 63, nt = (t >> 9) & 3, ks = t >> 11;  // ks 0..31
  int k = ks * 32 + ((lane >> 4) << 3) + j;   // 0..1023
  int o = nt * 16 + (lane & 15);
  bp[t] = f2bf(cw[o * 2048 + k]);
}

// ---------- K0a2: folded x_feats weights -> bpk2 B-frag bf16 (K=128) ----------
// k = s*8 + j' ; j'<7: CW2M[o][(j',s)] = sum_c cw[o][1024+c*16+s]*mlp_w[c*7+j']
//                j'==7: sum_c cw[o][1024+c*16+s]*mlp_b[c]
__global__ void k_pack_cw2(const float* __restrict__ cw, const float* __restrict__ mlp_w,
                           const float* __restrict__ mlp_b, unsigned short* __restrict__ bp2) {
  int t = blockIdx.x * 256 + threadIdx.x;  // 8192
  int jj = t & 7, lane = (t >> 3) & 63, nt = (t >> 9) & 3, ks2 = t >> 11;  // ks2 0..3
  int k = ks2 * 32 + ((lane >> 4) << 3) + jj;  // 0..127
  int s = k >> 3, j = k & 7;
  int o = nt * 16 + (lane & 15);
  float acc = 0.0f;
  for (int c = 0; c < 64; ++c) {
    float coef = (j < 7) ? mlp_w[c * 7 + j] : mlp_b[c];
    acc = fmaf(cw[o * 2048 + 1024 + c * 16 + s], coef, acc);
  }
  bp2[t] = f2bf(acc);
}

// ---------- K0b: feature [B][C][N] -> ftT [B][N][C] bf16 ----------
__global__ void k_transpose_ft(const float* __restrict__ f, unsigned short* __restrict__ ft) {
  __shared__ float tile[64][65];
  int b = blockIdx.x >> 6;
  int n0 = (blockIdx.x & 63) * 64;
  int lane = threadIdx.x & 63;
  int rr = threadIdx.x >> 6;  // 0..3
#pragma unroll
  for (int c0 = 0; c0 < 64; c0 += 4) {
    int c = c0 + rr;
    tile[c][lane] = f[(b * 64 + c) * 4096 + n0 + lane];
  }
  __syncthreads();
#pragma unroll
  for (int m0 = 0; m0 < 64; m0 += 4) {
    int nn = m0 + rr;
    ft[(b * 4096 + n0 + nn) * 64 + lane] = f2bf(tile[lane][nn]);
  }
}

// ---------- K1: KNN v3 (unchanged) ----------
__device__ __noinline__ void knn_full(const float4* __restrict__ pts, int n, int lane,
                                      int g, int* __restrict__ idxOut) {
  const int M = 24;
  float4 qp = pts[n];
  float qx = qp.x, qy = qp.y, qz = qp.z;
  float v[M];
  int id[M];
#pragma unroll
  for (int r = 0; r < M; ++r) { v[r] = FLT_MAX; id[r] = 0x7fffffff; }
  for (int i = 0; i < 64; ++i) {
    int j = (i << 6) | lane;
    float4 p = pts[j];
    float dx = p.x - qx, dy = p.y - qy, dz = p.z - qz;
    float d2 = fmaf(dx, dx, fmaf(dy, dy, dz * dz));
    bool c[M];
#pragma unroll
    for (int r = 0; r < M; ++r) c[r] = d2 < v[r];
#pragma unroll
    for (int r = M - 1; r >= 1; --r) {
      v[r] = c[r - 1] ? v[r - 1] : (c[r] ? d2 : v[r]);
      id[r] = c[r - 1] ? id[r - 1] : (c[r] ? j : id[r]);
    }
    v[0] = c[0] ? d2 : v[0];
    id[0] = c[0] ? j : id[0];
  }
  unsigned long long key = ((unsigned long long)__float_as_uint(v[0]) << 32) | (unsigned)id[0];
  unsigned long long ext = ~0ull;
  for (int r = 0; r < 24; ++r) {
    unsigned long long k = key;
#pragma unroll
    for (int s = 1; s < 64; s <<= 1) {
      unsigned long long o = __shfl_xor(k, s, 64);
      k = (o < k) ? o : k;
    }
    if (lane == r) ext = k;
    if (key == k) {
#pragma unroll
      for (int q = 0; q < M - 1; ++q) { v[q] = v[q + 1]; id[q] = id[q + 1]; }
      v[M - 1] = FLT_MAX;
      id[M - 1] = 0x7fffffff;
      key = ((unsigned long long)__float_as_uint(v[0]) << 32) | (unsigned)id[0];
    }
  }
  int ei = (int)(unsigned)(ext & 0xffffffffu);
  bool al = lane < 24;
  double dv = -1.0;
  if (al) {
    float4 p = pts[ei];
    double dx = (double)p.x - (double)qx;
    double dy = (double)p.y - (double)qy;
    double dz = (double)p.z - (double)qz;
    dv = dx * dx + dy * dy + dz * dz;
  }
#pragma unroll
  for (int r = 0; r < 4; ++r) {
    double bd = al ? dv : -1.0;
    int bi = al ? ei : -1;
#pragma unroll
    for (int s = 1; s < 64; s <<= 1) {
      double od = __shfl_xor(bd, s, 64);
      int oi = __shfl_xor(bi, s, 64);
      if (od > bd || (od == bd && oi > bi)) { bd = od; bi = oi; }
    }
    if (al && ei == bi) al = false;
  }
  unsigned long long msk = __ballot(al && ei != n);
  if (al) {
    if (ei == n) {
      idxOut[g * 20] = n;
    } else {
      int pos = 1 + __popcll(msk & ((1ull << lane) - 1ull));
      idxOut[g * 20 + pos] = ei;
    }
  }
}

__launch_bounds__(1024, 8)
__global__ void k_knn(const float* __restrict__ x, int* __restrict__ idxOut) {
  __shared__ float4 pts[4096];  // 64KB: (x,y,z,xx)
  int b = blockIdx.x >> 8;
  const float* xb = x + b * 3 * 4096;
  for (int i = threadIdx.x; i < 4096; i += 1024) {
    float px = xb[i], py = xb[4096 + i], pz = xb[8192 + i];
    pts[i] = make_float4(px, py, pz, fmaf(px, px, fmaf(py, py, pz * pz)));
  }
  __syncthreads();

  int lane = threadIdx.x & 63;
  int n = ((blockIdx.x & 255) << 4) + (threadIdx.x >> 6);
  int g = b * 4096 + n;

  float4 qp = pts[n];
  float m2x = -2.0f * qp.x, m2y = -2.0f * qp.y, m2z = -2.0f * qp.z;

  float v = FLT_MAX;
#pragma unroll 4
  for (int i = 0; i < 64; ++i) {
    float4 p = pts[(i << 6) | lane];
    float d = fmaf(m2z, p.z, fmaf(m2y, p.y, fmaf(m2x, p.x, p.w)));
    v = fminf(v, d);
  }

#pragma unroll
  for (int k = 2; k <= 64; k <<= 1) {
#pragma unroll
    for (int j = k >> 1; j > 0; j >>= 1) {
      float o = __shfl_xor(v, j, 64);
      bool up = ((lane & k) == 0);
      bool lower = ((lane & j) == 0);
      float mn = fminf(v, o), mx = fmaxf(v, o);
      v = (up == lower) ? mn : mx;
    }
  }
  float T = __shfl(v, 23, 64);

  int ei = -1;
  int base = 0;
  bool ovf = false;
#pragma unroll 2
  for (int i = 0; i < 64; ++i) {
    int j = (i << 6) | lane;
    float4 p = pts[j];
    float d = fmaf(m2z, p.z, fmaf(m2y, p.y, fmaf(m2x, p.x, p.w)));
    bool pred = (d <= T);
    unsigned long long mask = __ballot(pred);
    if (mask) {
      int cnt = __popcll(mask);
      if (base + cnt > 63) {
        ovf = true;
      } else {
        int dst = pred ? (base + __popcll(mask & ((1ull << lane) - 1ull))) : 63;
        int got = __builtin_amdgcn_ds_permute(dst << 2, j);
        bool recv = (lane >= base) && (lane < base + cnt);
        ei = recv ? got : ei;
      }
      base += cnt;
    }
  }

  bool ok = !ovf;
  if (ok) {
    bool act = lane < base;
    double dm = 1e300;
    if (act) {
      float4 p = pts[ei];
      double dx = (double)p.x - (double)qp.x;
      double dy = (double)p.y - (double)qp.y;
      double dz = (double)p.z - (double)qp.z;
      dm = dx * dx + dy * dy + dz * dz;
    }
    int rank = 0;
    for (int r = 0; r < base; ++r) {
      double dr = __shfl(dm, r, 64);
      int ir = __shfl(ei, r, 64);
      bool less = (dr < dm) || (dr == dm && ir < ei);
      rank += less ? 1 : 0;
    }
    bool keep = act && (rank < 20);
    bool isSelf = keep && (ei == n);
    unsigned long long smask = __ballot(isSelf);
    ok = (smask != 0ull);
    if (ok) {
      if (isSelf) idxOut[g * 20] = n;
      unsigned long long msk = __ballot(keep && !isSelf);
      if (keep && !isSelf) {
        int pos = 1 + __popcll(msk & ((1ull << lane) - 1ull));
        idxOut[g * 20 + pos] = ei;
      }
    }
  }
  if (!ok) knn_full(pts, n, lane, g, idxOut);
}

// ---------- K2: fused features + aw + agg(feature half) + F' + MFMA conv ----------
// 8 points/block, 256 threads (4 waves), ~34KB LDS -> 4 blocks/CU.
__launch_bounds__(256, 4)
__global__ void k_main(const float* __restrict__ x, const float* __restrict__ feat,
                       const unsigned short* __restrict__ ftT, int useFtT,
                       const float* __restrict__ kern,
                       const unsigned short* __restrict__ bpk,
                       const unsigned short* __restrict__ bpk2,
                       const float* __restrict__ conv_b, const int* __restrict__ idxIn,
                       float* __restrict__ out) {
  // agg FIRST: MFMA A-frag reads rows r=0..15 (rows 8..15 are harmless overreads
  // into the arrays below; per-row GEMM independence discards them).
  __shared__ __align__(16) unsigned short agg[BPTS][1024];  // 16KB; reused as f32 red
  __shared__ float awL[BPTS][20][16];                       // 10.25KB
  __shared__ __align__(16) float4 f7s[BPTS][20];            // 2.5KB (rx,ry,rz,dis)
  __shared__ __align__(16) unsigned short fpA[16][128];     // 4KB F' A-tile (rows 8..15 unused)
  __shared__ __align__(16) float4 qL[BPTS];                 // 128B
  __shared__ int idxL[BPTS][20];

  int t = threadIdx.x;
  int lane = t & 63;
  int w = t >> 6;
  // XCD swizzle: batch = blockIdx&7 pins each batch's ftT slice in one XCD L2.
  int b = blockIdx.x & 7;
  int n0 = (blockIdx.x >> 3) * BPTS;
  int g0 = b * 4096 + n0;
  const float* xb = x + b * 3 * 4096;

  // ---- step 0: geometry (8 pts x 20 nbrs) ----
  {
    int pt = t >> 5, slot = t & 31;
    int n = n0 + pt;
    float qx = xb[n], qy = xb[4096 + n], qz = xb[8192 + n];
    if (slot < 20) {
      int kk = idxIn[(g0 + pt) * 20 + slot];
      idxL[pt][slot] = kk;
      float rx = xb[kk] - qx, ry = xb[4096 + kk] - qy, rz = xb[8192 + kk] - qz;
      float ds = sqrtf(rx * rx + ry * ry + rz * rz);
      f7s[pt][slot] = make_float4(rx, ry, rz, ds);
    } else if (slot == 20) {
      qL[pt] = make_float4(qx, qy, qz, 0.0f);
    }
  }
  __syncthreads();

  // ---- step 1: raw aw + normalization chain (regs) + awL write + F' build ----
  if (t < 128) {
    int pt = t >> 4, s = t & 15;
    float kx = kern[s], ky = kern[16 + s], kz = kern[32 + s];
    float wv[20];
#pragma unroll
    for (int k = 0; k < 20; ++k) {
      float4 f = f7s[pt][k];
      float dot = f.x * kx + f.y * ky + f.z * kz;
      if (s == 0 && k == 0) dot += 1.0f;
      wv[k] = dot > 0.0f ? dot : 0.0f;
    }
    float sum = 0.0f;
#pragma unroll
    for (int k = 0; k < 20; ++k) sum += wv[k];
    float inv1 = 1.0f / (sum + 1e-6f);
    float sum2 = 0.0f;
#pragma unroll
    for (int k = 0; k < 20; ++k) {
      float u = wv[k] * inv1;
      sum2 += u * u;
    }
    float inv2 = 1.0f / (sum2 + 1e-6f);
    float colsum = 0.0f;
    float F0 = 0.0f, F1 = 0.0f, F2 = 0.0f, F3 = 0.0f;
#pragma unroll
    for (int k = 0; k < 20; ++k) {
      float u = wv[k] * inv1;
      u = u * u * inv2;
      u = (u > 0.1f) ? u : 0.0f;
      awL[pt][k][s] = u;
      colsum += u;
      float4 f = f7s[pt][k];
      F0 = fmaf(f.x, u, F0);
      F1 = fmaf(f.y, u, F1);
      F2 = fmaf(f.z, u, F2);
      F3 = fmaf(f.w, u, F3);
    }
    float4 q = qL[pt];
    __align__(16) unsigned short tmp[8];
    tmp[0] = f2bf(q.x * colsum);
    tmp[1] = f2bf(q.y * colsum);
    tmp[2] = f2bf(q.z * colsum);
    tmp[3] = f2bf(F0);
    tmp[4] = f2bf(F1);
    tmp[5] = f2bf(F2);
    tmp[6] = f2bf(F3);
    tmp[7] = f2bf(colsum);
    // F' A-layout row pt, k-chunk s (16B), XOR-swizzled by row
    *(uint4*)((char*)&fpA[0][0] + pt * 256 + ((s ^ (pt & 7)) << 4)) = *(uint4*)tmp;
  }
  __syncthreads();

  // ---- phase A1: feature half agg (K = 0..1023) ----
#pragma unroll
  for (int half = 0; half < 2; ++half) {
    int pt = (w << 1) + half;
    int c = lane;
    float fv[20];
    if (useFtT) {
#pragma unroll
      for (int k = 0; k < 20; ++k) fv[k] = bf2f(ftT[(b * 4096 + idxL[pt][k]) * 64 + c]);
    } else {
      const float* fb = feat + (b * 64 + c) * 4096;
#pragma unroll
      for (int k = 0; k < 20; ++k) fv[k] = fb[idxL[pt][k]];
    }
    float a1[16];
#pragma unroll
    for (int s = 0; s < 16; ++s) a1[s] = 0.0f;
#pragma unroll
    for (int k = 0; k < 20; ++k) {
      float a = fv[k];
#pragma unroll
      for (int s = 0; s < 16; ++s) a1[s] = fmaf(a, awL[pt][k][s], a1[s]);
    }
    __align__(16) unsigned short tmp[16];
#pragma unroll
    for (int s = 0; s < 16; ++s) tmp[s] = f2bf(a1[s]);
    char* rb = (char*)&agg[pt][0];
    int sw = (pt & 7) << 4;
    *(uint4*)(rb + ((c * 32) ^ sw)) = *(uint4*)&tmp[0];
    *(uint4*)(rb + ((c * 32 + 16) ^ sw)) = *(uint4*)&tmp[8];
  }
  __syncthreads();

  // ---- GEMM: K=1024 (agg) + K=128 (F') accumulated into same acc ----
  f32x4 acc[4];
#pragma unroll
  for (int nt = 0; nt < 4; ++nt) acc[nt] = (f32x4){0.f, 0.f, 0.f, 0.f};
  {
    int r = lane & 15;
    const char* rowbase = (const char*)&agg[0][0] + r * 2048;
#pragma unroll
    for (int ks = 0; ks < 8; ++ks) {
      int ksl = w * 8 + ks;
      int off = (ksl * 64 + ((lane >> 4) << 4)) ^ ((r & 7) << 4);
      short8 af = *(const short8*)(rowbase + off);
#pragma unroll
      for (int nt = 0; nt < 4; ++nt) {
        short8 bf = *(const short8*)(bpk + (((ksl * 4 + nt) * 64 + lane) << 3));
        acc[nt] = __builtin_amdgcn_mfma_f32_16x16x32_bf16(af, bf, acc[nt], 0, 0, 0);
      }
    }
    // F' pass: ks2 = w (each wave one K=32 chunk of 128)
    {
      int chunk = (w << 2) + (lane >> 4);  // 0..15
      short8 af = *(const short8*)((const char*)&fpA[0][0] + r * 256 + ((chunk ^ (r & 7)) << 4));
#pragma unroll
      for (int nt = 0; nt < 4; ++nt) {
        short8 bf = *(const short8*)(bpk2 + ((((w << 2) + nt) * 64 + lane) << 3));
        acc[nt] = __builtin_amdgcn_mfma_f32_16x16x32_bf16(af, bf, acc[nt], 0, 0, 0);
      }
    }
  }
  __syncthreads();  // before reusing agg as red

  // ---- cross-wave reduce (red reuses agg region) ----
  float* red = (float*)&agg[0][0];  // 4*8*64*4 = 8KB of 16KB
  {
#pragma unroll
    for (int nt = 0; nt < 4; ++nt)
#pragma unroll
      for (int r = 0; r < 4; ++r) {
        int row = ((lane >> 4) << 2) + r;  // 0..15; only 0..7 valid
        if (row < 8) {
          int o = nt * 16 + (lane & 15);
          red[(w * 8 + row) * 64 + (o ^ ((row & 7) << 2))] = acc[nt][r];
        }
      }
  }
  __syncthreads();
#pragma unroll
  for (int rep = 0; rep < 2; ++rep) {
    int u = rep * 256 + t;
    int pt = u & 7, o = u >> 3;
    float s = conv_b[o];
#pragma unroll
    for (int w2 = 0; w2 < 4; ++w2) s += red[(w2 * 8 + pt) * 64 + (o ^ ((pt & 7) << 2))];
    out[(b * 64 + o) * 4096 + n0 + pt] = s;
  }
}

// ---------- K3a: BN stats ----------
__global__ void k_bnstats(const float* __restrict__ out, const float* __restrict__ gamma,
                          const float* __restrict__ beta, float* __restrict__ stats) {
  __shared__ double rs[256], rq[256];
  int o = blockIdx.x;
  double s = 0.0, q = 0.0;
  for (int b = 0; b < 8; ++b) {
    const float* p = out + (b * 64 + o) * 4096;
    for (int i = threadIdx.x; i < 4096; i += 256) {
      double v = (double)p[i];
      s += v;
      q += v * v;
    }
  }
  rs[threadIdx.x] = s;
  rq[threadIdx.x] = q;
  __syncthreads();
  for (int st = 128; st > 0; st >>= 1) {
    if ((int)threadIdx.x < st) {
      rs[threadIdx.x] += rs[threadIdx.x + st];
      rq[threadIdx.x] += rq[threadIdx.x + st];
    }
    __syncthreads();
  }
  if (threadIdx.x == 0) {
    double mean = rs[0] / 32768.0;
    double var = rq[0] / 32768.0 - mean * mean;
    double inv = 1.0 / sqrt(var + 1e-5);
    double sc = (double)gamma[o] * inv;
    stats[o * 2] = (float)sc;
    stats[o * 2 + 1] = (float)((double)beta[o] - mean * sc);
  }
}

// ---------- K3b: BN apply ----------
__global__ void k_bnapply(float* __restrict__ out, const float* __restrict__ stats) {
  int i = blockIdx.x * 256 + threadIdx.x;
  int o = (i >> 12) & 63;
  out[i] = fmaf(out[i], stats[o * 2], stats[o * 2 + 1]);
}

extern "C" void kernel_launch(void* const* d_in, const int* in_sizes, int n_in,
                              void* d_out, int out_size, void* d_ws, size_t ws_size,
                              hipStream_t stream) {
  const float* x = (const float*)d_in[0];
  const float* feat = (const float*)d_in[1];
  const float* kern = (const float*)d_in[2];
  const float* mlp_w = (const float*)d_in[3];
  const float* mlp_b = (const float*)d_in[4];
  const float* conv_w = (const float*)d_in[5];
  const float* conv_b = (const float*)d_in[6];
  const float* gamma = (const float*)d_in[7];
  const float* beta = (const float*)d_in[8];
  float* out = (float*)d_out;
  char* ws = (char*)d_ws;

  // workspace layout
  int* idx = (int*)ws;                                    // 2,621,440 B
  float* stats = (float*)(ws + 2621440);                  // pad to 4KB
  unsigned short* bpk = (unsigned short*)(ws + 2625536);  // 131,072 B (K=1024)
  unsigned short* bpk2 = (unsigned short*)(ws + 2756608); // 16,384 B  (K=128)
  unsigned short* ftT = (unsigned short*)(ws + 2772992);  // 4,194,304 B
  int useFtT = (ws_size >= (size_t)(2772992 + 4194304)) ? 1 : 0;

  k_pack_cw<<<256, 256, 0, stream>>>(conv_w, bpk);
  k_pack_cw2<<<32, 256, 0, stream>>>(conv_w, mlp_w, mlp_b, bpk2);
  if (useFtT) k_transpose_ft<<<512, 256, 0, stream>>>(feat, ftT);
  k_knn<<<2048, 1024, 0, stream>>>(x, idx);
  k_main<<<4096, 256, 0, stream>>>(x, feat, ftT, useFtT, kern, bpk, bpk2,
                                   conv_b, idx, out);
  k_bnstats<<<64, 256, 0, stream>>>(out, gamma, beta, stats);
  k_bnapply<<<8192, 256, 0, stream>>>(out, stats);
}

// Round 7
// 202.063 us; speedup vs baseline: 1.3246x; 1.0416x over previous
//
#include <hip/hip_runtime.h>
#include <cfloat>
#include <math.h>

#define NB 8
#define NPT 4096
#define NC 64
#define KNN 20
#define KSZ 16
#define BPTS 8

typedef __attribute__((ext_vector_type(8))) short short8;
typedef __attribute__((ext_vector_type(4))) float f32x4;

// ---------- helpers ----------
__device__ __forceinline__ unsigned short f2bf(float f) {
  unsigned u = __float_as_uint(f);
  unsigned r = (u + 0x7fffu + ((u >> 16) & 1u)) >> 16;
  return (unsigned short)r;
}
__device__ __forceinline__ float bf2f(unsigned short h) {
  return __uint_as_float(((unsigned)h) << 16);
}

// ---------- K0a: conv_w lower half [64][0..1023] -> bpk B-frag bf16 (K=1024) ----------
__global__ void k_pack_cw(const float* __restrict__ cw, unsigned short* __restrict__ bp) {
  int t = blockIdx.x * 256 + threadIdx.x;  // 65536
  int j = t & 7, lane = (t >> 3) & 63, nt = (t >> 9) & 3, ks = t >> 11;  // ks 0..31
  int k = ks * 32 + ((lane >> 4) << 3) + j;   // 0..1023
  int o = nt * 16 + (lane & 15);
  bp[t] = f2bf(cw[o * 2048 + k]);
}

// ---------- K0a2: folded x_feats weights -> bpk2 B-frag bf16 (K=128) ----------
__global__ void k_pack_cw2(const float* __restrict__ cw, const float* __restrict__ mlp_w,
                           const float* __restrict__ mlp_b, unsigned short* __restrict__ bp2) {
  int t = blockIdx.x * 256 + threadIdx.x;  // 8192
  int jj = t & 7, lane = (t >> 3) & 63, nt = (t >> 9) & 3, ks2 = t >> 11;  // ks2 0..3
  int k = ks2 * 32 + ((lane >> 4) << 3) + jj;  // 0..127
  int s = k >> 3, j = k & 7;
  int o = nt * 16 + (lane & 15);
  float acc = 0.0f;
  for (int c = 0; c < 64; ++c) {
    float coef = (j < 7) ? mlp_w[c * 7 + j] : mlp_b[c];
    acc = fmaf(cw[o * 2048 + 1024 + c * 16 + s], coef, acc);
  }
  bp2[t] = f2bf(acc);
}

// ---------- K0b: feature [B][C][N] -> ftT [B][N][C] bf16 ----------
__global__ void k_transpose_ft(const float* __restrict__ f, unsigned short* __restrict__ ft) {
  __shared__ float tile[64][65];
  int b = blockIdx.x >> 6;
  int n0 = (blockIdx.x & 63) * 64;
  int lane = threadIdx.x & 63;
  int rr = threadIdx.x >> 6;  // 0..3
#pragma unroll
  for (int c0 = 0; c0 < 64; c0 += 4) {
    int c = c0 + rr;
    tile[c][lane] = f[(b * 64 + c) * 4096 + n0 + lane];
  }
  __syncthreads();
#pragma unroll
  for (int m0 = 0; m0 < 64; m0 += 4) {
    int nn = m0 + rr;
    ft[(b * 4096 + n0 + nn) * 64 + lane] = f2bf(tile[lane][nn]);
  }
}

// ---------- K1: KNN v4 — 4 rows per wave ----------
__device__ __noinline__ void knn_full(const float4* __restrict__ pts, int n, int lane,
                                      int g, int* __restrict__ idxOut) {
  const int M = 24;
  float4 qp = pts[n];
  float qx = qp.x, qy = qp.y, qz = qp.z;
  float v[M];
  int id[M];
#pragma unroll
  for (int r = 0; r < M; ++r) { v[r] = FLT_MAX; id[r] = 0x7fffffff; }
  for (int i = 0; i < 64; ++i) {
    int j = (i << 6) | lane;
    float4 p = pts[j];
    float dx = p.x - qx, dy = p.y - qy, dz = p.z - qz;
    float d2 = fmaf(dx, dx, fmaf(dy, dy, dz * dz));
    bool c[M];
#pragma unroll
    for (int r = 0; r < M; ++r) c[r] = d2 < v[r];
#pragma unroll
    for (int r = M - 1; r >= 1; --r) {
      v[r] = c[r - 1] ? v[r - 1] : (c[r] ? d2 : v[r]);
      id[r] = c[r - 1] ? id[r - 1] : (c[r] ? j : id[r]);
    }
    v[0] = c[0] ? d2 : v[0];
    id[0] = c[0] ? j : id[0];
  }
  unsigned long long key = ((unsigned long long)__float_as_uint(v[0]) << 32) | (unsigned)id[0];
  unsigned long long ext = ~0ull;
  for (int r = 0; r < 24; ++r) {
    unsigned long long k = key;
#pragma unroll
    for (int s = 1; s < 64; s <<= 1) {
      unsigned long long o = __shfl_xor(k, s, 64);
      k = (o < k) ? o : k;
    }
    if (lane == r) ext = k;
    if (key == k) {
#pragma unroll
      for (int q = 0; q < M - 1; ++q) { v[q] = v[q + 1]; id[q] = id[q + 1]; }
      v[M - 1] = FLT_MAX;
      id[M - 1] = 0x7fffffff;
      key = ((unsigned long long)__float_as_uint(v[0]) << 32) | (unsigned)id[0];
    }
  }
  int ei = (int)(unsigned)(ext & 0xffffffffu);
  bool al = lane < 24;
  double dv = -1.0;
  if (al) {
    float4 p = pts[ei];
    double dx = (double)p.x - (double)qx;
    double dy = (double)p.y - (double)qy;
    double dz = (double)p.z - (double)qz;
    dv = dx * dx + dy * dy + dz * dz;
  }
#pragma unroll
  for (int r = 0; r < 4; ++r) {
    double bd = al ? dv : -1.0;
    int bi = al ? ei : -1;
#pragma unroll
    for (int s = 1; s < 64; s <<= 1) {
      double od = __shfl_xor(bd, s, 64);
      int oi = __shfl_xor(bi, s, 64);
      if (od > bd || (od == bd && oi > bi)) { bd = od; bi = oi; }
    }
    if (al && ei == bi) al = false;
  }
  unsigned long long msk = __ballot(al && ei != n);
  if (al) {
    if (ei == n) {
      idxOut[g * 20] = n;
    } else {
      int pos = 1 + __popcll(msk & ((1ull << lane) - 1ull));
      idxOut[g * 20 + pos] = ei;
    }
  }
}

__launch_bounds__(1024, 2)
__global__ void k_knn(const float* __restrict__ x, int* __restrict__ idxOut) {
  __shared__ float4 pts[4096];  // 64KB: (x,y,z,xx)
  int b = blockIdx.x >> 6;      // 64 blocks/batch, 64 rows/block
  const float* xb = x + b * 3 * 4096;
  for (int i = threadIdx.x; i < 4096; i += 1024) {
    float px = xb[i], py = xb[4096 + i], pz = xb[8192 + i];
    pts[i] = make_float4(px, py, pz, fmaf(px, px, fmaf(py, py, pz * pz)));
  }
  __syncthreads();

  int lane = threadIdx.x & 63;
  int w = threadIdx.x >> 6;
  int nb = ((blockIdx.x & 63) << 6) + (w << 2);  // first of this wave's 4 rows
  int gb = b * 4096 + nb;

  float m2x[4], m2y[4], m2z[4];
#pragma unroll
  for (int r = 0; r < 4; ++r) {
    float4 q = pts[nb + r];
    m2x[r] = -2.0f * q.x;
    m2y[r] = -2.0f * q.y;
    m2z[r] = -2.0f * q.z;
  }

  // ---- pass 1: per-lane min for 4 rows (one candidate load serves 4 rows) ----
  float v[4];
#pragma unroll
  for (int r = 0; r < 4; ++r) v[r] = FLT_MAX;
#pragma unroll 2
  for (int i = 0; i < 64; ++i) {
    float4 p = pts[(i << 6) | lane];
#pragma unroll
    for (int r = 0; r < 4; ++r) {
      float d = fmaf(m2z[r], p.z, fmaf(m2y[r], p.y, fmaf(m2x[r], p.x, p.w)));
      v[r] = fminf(v[r], d);
    }
  }

  // ---- bitonic sort each row's 64 lane minima (shared stage masks) ----
#pragma unroll
  for (int k = 2; k <= 64; k <<= 1) {
#pragma unroll
    for (int j = k >> 1; j > 0; j >>= 1) {
      bool sel = ((lane & k) == 0) == ((lane & j) == 0);
#pragma unroll
      for (int r = 0; r < 4; ++r) {
        float o = __shfl_xor(v[r], j, 64);
        float mn = fminf(v[r], o), mx = fmaxf(v[r], o);
        v[r] = sel ? mn : mx;
      }
    }
  }
  float T[4];
#pragma unroll
  for (int r = 0; r < 4; ++r) T[r] = __shfl(v[r], 23, 64);  // >= f32 rank-24 of full row

  // ---- pass 2: collect all d' <= T per row, compact via ds_permute ----
  int ei[4], base[4];
  bool ovf[4];
#pragma unroll
  for (int r = 0; r < 4; ++r) { ei[r] = -1; base[r] = 0; ovf[r] = false; }
#pragma unroll 2
  for (int i = 0; i < 64; ++i) {
    float4 p = pts[(i << 6) | lane];
#pragma unroll
    for (int r = 0; r < 4; ++r) {
      float d = fmaf(m2z[r], p.z, fmaf(m2y[r], p.y, fmaf(m2x[r], p.x, p.w)));
      bool pred = (d <= T[r]);
      unsigned long long mask = __ballot(pred);
      if (mask) {
        int cnt = __popcll(mask);
        if (base[r] + cnt > 63) {
          ovf[r] = true;
        } else {
          int dst = pred ? (base[r] + __popcll(mask & ((1ull << lane) - 1ull))) : 63;
          int got = __builtin_amdgcn_ds_permute(dst << 2, (i << 6) | lane);
          bool recv = (lane >= base[r]) && (lane < base[r] + cnt);
          ei[r] = recv ? got : ei[r];
        }
        base[r] += cnt;
      }
    }
  }

  // ---- per-row exact f64 lex rank-by-count + write ----
#pragma unroll
  for (int r = 0; r < 4; ++r) {
    int n = nb + r, g = gb + r;
    bool ok = !ovf[r];
    if (ok) {
      float4 qp = pts[n];
      bool act = lane < base[r];
      int e = ei[r];
      double dm = 1e300;
      if (act) {
        float4 p = pts[e];
        double dx = (double)p.x - (double)qp.x;
        double dy = (double)p.y - (double)qp.y;
        double dz = (double)p.z - (double)qp.z;
        dm = dx * dx + dy * dy + dz * dz;
      }
      int rank = 0;
      for (int r2 = 0; r2 < base[r]; ++r2) {
        double dr = __shfl(dm, r2, 64);
        int ir = __shfl(e, r2, 64);
        bool less = (dr < dm) || (dr == dm && ir < e);
        rank += less ? 1 : 0;
      }
      bool keep = act && (rank < 20);
      bool isSelf = keep && (e == n);
      unsigned long long smask = __ballot(isSelf);
      ok = (smask != 0ull);
      if (ok) {
        if (isSelf) idxOut[g * 20] = n;
        unsigned long long msk = __ballot(keep && !isSelf);
        if (keep && !isSelf) {
          int pos = 1 + __popcll(msk & ((1ull << lane) - 1ull));
          idxOut[g * 20 + pos] = e;
        }
      }
    }
    if (!ok) knn_full(pts, n, lane, g, idxOut);
  }
}

// ---------- K2: fused features + aw + agg(feature half) + F' + MFMA conv ----------
// 8 points/block, 256 threads (4 waves), ~34KB LDS -> 4 blocks/CU.
__launch_bounds__(256, 4)
__global__ void k_main(const float* __restrict__ x, const float* __restrict__ feat,
                       const unsigned short* __restrict__ ftT, int useFtT,
                       const float* __restrict__ kern,
                       const unsigned short* __restrict__ bpk,
                       const unsigned short* __restrict__ bpk2,
                       const float* __restrict__ conv_b, const int* __restrict__ idxIn,
                       float* __restrict__ out) {
  __shared__ __align__(16) unsigned short agg[BPTS][1024];  // 16KB; reused as f32 red
  __shared__ float awL[BPTS][20][16];                       // 10.25KB
  __shared__ __align__(16) float4 f7s[BPTS][20];            // 2.5KB (rx,ry,rz,dis)
  __shared__ __align__(16) unsigned short fpA[16][128];     // 4KB F' A-tile (rows 8..15 unused)
  __shared__ __align__(16) float4 qL[BPTS];                 // 128B
  __shared__ int idxL[BPTS][20];

  int t = threadIdx.x;
  int lane = t & 63;
  int w = t >> 6;
  // XCD swizzle: batch = blockIdx&7 pins each batch's ftT slice in one XCD L2.
  int b = blockIdx.x & 7;
  int n0 = (blockIdx.x >> 3) * BPTS;
  int g0 = b * 4096 + n0;
  const float* xb = x + b * 3 * 4096;

  // ---- step 0: geometry (8 pts x 20 nbrs) ----
  {
    int pt = t >> 5, slot = t & 31;
    int n = n0 + pt;
    float qx = xb[n], qy = xb[4096 + n], qz = xb[8192 + n];
    if (slot < 20) {
      int kk = idxIn[(g0 + pt) * 20 + slot];
      idxL[pt][slot] = kk;
      float rx = xb[kk] - qx, ry = xb[4096 + kk] - qy, rz = xb[8192 + kk] - qz;
      float ds = sqrtf(rx * rx + ry * ry + rz * rz);
      f7s[pt][slot] = make_float4(rx, ry, rz, ds);
    } else if (slot == 20) {
      qL[pt] = make_float4(qx, qy, qz, 0.0f);
    }
  }
  __syncthreads();

  // ---- step 1: raw aw + normalization chain (regs) + awL write + F' build ----
  if (t < 128) {
    int pt = t >> 4, s = t & 15;
    float kx = kern[s], ky = kern[16 + s], kz = kern[32 + s];
    float wv[20];
#pragma unroll
    for (int k = 0; k < 20; ++k) {
      float4 f = f7s[pt][k];
      float dot = f.x * kx + f.y * ky + f.z * kz;
      if (s == 0 && k == 0) dot += 1.0f;
      wv[k] = dot > 0.0f ? dot : 0.0f;
    }
    float sum = 0.0f;
#pragma unroll
    for (int k = 0; k < 20; ++k) sum += wv[k];
    float inv1 = 1.0f / (sum + 1e-6f);
    float sum2 = 0.0f;
#pragma unroll
    for (int k = 0; k < 20; ++k) {
      float u = wv[k] * inv1;
      sum2 += u * u;
    }
    float inv2 = 1.0f / (sum2 + 1e-6f);
    float colsum = 0.0f;
    float F0 = 0.0f, F1 = 0.0f, F2 = 0.0f, F3 = 0.0f;
#pragma unroll
    for (int k = 0; k < 20; ++k) {
      float u = wv[k] * inv1;
      u = u * u * inv2;
      u = (u > 0.1f) ? u : 0.0f;
      awL[pt][k][s] = u;
      colsum += u;
      float4 f = f7s[pt][k];
      F0 = fmaf(f.x, u, F0);
      F1 = fmaf(f.y, u, F1);
      F2 = fmaf(f.z, u, F2);
      F3 = fmaf(f.w, u, F3);
    }
    float4 q = qL[pt];
    __align__(16) unsigned short tmp[8];
    tmp[0] = f2bf(q.x * colsum);
    tmp[1] = f2bf(q.y * colsum);
    tmp[2] = f2bf(q.z * colsum);
    tmp[3] = f2bf(F0);
    tmp[4] = f2bf(F1);
    tmp[5] = f2bf(F2);
    tmp[6] = f2bf(F3);
    tmp[7] = f2bf(colsum);
    *(uint4*)((char*)&fpA[0][0] + pt * 256 + ((s ^ (pt & 7)) << 4)) = *(uint4*)tmp;
  }
  __syncthreads();

  // ---- phase A1: feature half agg (K = 0..1023) ----
#pragma unroll
  for (int half = 0; half < 2; ++half) {
    int pt = (w << 1) + half;
    int c = lane;
    float fv[20];
    if (useFtT) {
#pragma unroll
      for (int k = 0; k < 20; ++k) fv[k] = bf2f(ftT[(b * 4096 + idxL[pt][k]) * 64 + c]);
    } else {
      const float* fb = feat + (b * 64 + c) * 4096;
#pragma unroll
      for (int k = 0; k < 20; ++k) fv[k] = fb[idxL[pt][k]];
    }
    float a1[16];
#pragma unroll
    for (int s = 0; s < 16; ++s) a1[s] = 0.0f;
#pragma unroll
    for (int k = 0; k < 20; ++k) {
      float a = fv[k];
#pragma unroll
      for (int s = 0; s < 16; ++s) a1[s] = fmaf(a, awL[pt][k][s], a1[s]);
    }
    __align__(16) unsigned short tmp[16];
#pragma unroll
    for (int s = 0; s < 16; ++s) tmp[s] = f2bf(a1[s]);
    char* rb = (char*)&agg[pt][0];
    int sw = (pt & 7) << 4;
    *(uint4*)(rb + ((c * 32) ^ sw)) = *(uint4*)&tmp[0];
    *(uint4*)(rb + ((c * 32 + 16) ^ sw)) = *(uint4*)&tmp[8];
  }
  __syncthreads();

  // ---- GEMM: K=1024 (agg) + K=128 (F') accumulated into same acc ----
  f32x4 acc[4];
#pragma unroll
  for (int nt = 0; nt < 4; ++nt) acc[nt] = (f32x4){0.f, 0.f, 0.f, 0.f};
  {
    int r = lane & 15;
    const char* rowbase = (const char*)&agg[0][0] + r * 2048;
#pragma unroll
    for (int ks = 0; ks < 8; ++ks) {
      int ksl = w * 8 + ks;
      int off = (ksl * 64 + ((lane >> 4) << 4)) ^ ((r & 7) << 4);
      short8 af = *(const short8*)(rowbase + off);
#pragma unroll
      for (int nt = 0; nt < 4; ++nt) {
        short8 bf = *(const short8*)(bpk + (((ksl * 4 + nt) * 64 + lane) << 3));
        acc[nt] = __builtin_amdgcn_mfma_f32_16x16x32_bf16(af, bf, acc[nt], 0, 0, 0);
      }
    }
    {
      int chunk = (w << 2) + (lane >> 4);  // 0..15
      short8 af = *(const short8*)((const char*)&fpA[0][0] + r * 256 + ((chunk ^ (r & 7)) << 4));
#pragma unroll
      for (int nt = 0; nt < 4; ++nt) {
        short8 bf = *(const short8*)(bpk2 + ((((w << 2) + nt) * 64 + lane) << 3));
        acc[nt] = __builtin_amdgcn_mfma_f32_16x16x32_bf16(af, bf, acc[nt], 0, 0, 0);
      }
    }
  }
  __syncthreads();  // before reusing agg as red

  // ---- cross-wave reduce ----
  float* red = (float*)&agg[0][0];  // 8KB of 16KB
  {
#pragma unroll
    for (int nt = 0; nt < 4; ++nt)
#pragma unroll
      for (int r = 0; r < 4; ++r) {
        int row = ((lane >> 4) << 2) + r;  // 0..15; only 0..7 valid
        if (row < 8) {
          int o = nt * 16 + (lane & 15);
          red[(w * 8 + row) * 64 + (o ^ ((row & 7) << 2))] = acc[nt][r];
        }
      }
  }
  __syncthreads();
#pragma unroll
  for (int rep = 0; rep < 2; ++rep) {
    int u = rep * 256 + t;
    int pt = u & 7, o = u >> 3;
    float s = conv_b[o];
#pragma unroll
    for (int w2 = 0; w2 < 4; ++w2) s += red[(w2 * 8 + pt) * 64 + (o ^ ((pt & 7) << 2))];
    out[(b * 64 + o) * 4096 + n0 + pt] = s;
  }
}

// ---------- K3a: BN stats ----------
__global__ void k_bnstats(const float* __restrict__ out, const float* __restrict__ gamma,
                          const float* __restrict__ beta, float* __restrict__ stats) {
  __shared__ double rs[256], rq[256];
  int o = blockIdx.x;
  double s = 0.0, q = 0.0;
  for (int b = 0; b < 8; ++b) {
    const float* p = out + (b * 64 + o) * 4096;
    for (int i = threadIdx.x; i < 4096; i += 256) {
      double v = (double)p[i];
      s += v;
      q += v * v;
    }
  }
  rs[threadIdx.x] = s;
  rq[threadIdx.x] = q;
  __syncthreads();
  for (int st = 128; st > 0; st >>= 1) {
    if ((int)threadIdx.x < st) {
      rs[threadIdx.x] += rs[threadIdx.x + st];
      rq[threadIdx.x] += rq[threadIdx.x + st];
    }
    __syncthreads();
  }
  if (threadIdx.x == 0) {
    double mean = rs[0] / 32768.0;
    double var = rq[0] / 32768.0 - mean * mean;
    double inv = 1.0 / sqrt(var + 1e-5);
    double sc = (double)gamma[o] * inv;
    stats[o * 2] = (float)sc;
    stats[o * 2 + 1] = (float)((double)beta[o] - mean * sc);
  }
}

// ---------- K3b: BN apply ----------
__global__ void k_bnapply(float* __restrict__ out, const float* __restrict__ stats) {
  int i = blockIdx.x * 256 + threadIdx.x;
  int o = (i >> 12) & 63;
  out[i] = fmaf(out[i], stats[o * 2], stats[o * 2 + 1]);
}

extern "C" void kernel_launch(void* const* d_in, const int* in_sizes, int n_in,
                              void* d_out, int out_size, void* d_ws, size_t ws_size,
                              hipStream_t stream) {
  const float* x = (const float*)d_in[0];
  const float* feat = (const float*)d_in[1];
  const float* kern = (const float*)d_in[2];
  const float* mlp_w = (const float*)d_in[3];
  const float* mlp_b = (const float*)d_in[4];
  const float* conv_w = (const float*)d_in[5];
  const float* conv_b = (const float*)d_in[6];
  const float* gamma = (const float*)d_in[7];
  const float* beta = (const float*)d_in[8];
  float* out = (float*)d_out;
  char* ws = (char*)d_ws;

  // workspace layout
  int* idx = (int*)ws;                                    // 2,621,440 B
  float* stats = (float*)(ws + 2621440);                  // pad to 4KB
  unsigned short* bpk = (unsigned short*)(ws + 2625536);  // 131,072 B (K=1024)
  unsigned short* bpk2 = (unsigned short*)(ws + 2756608); // 16,384 B  (K=128)
  unsigned short* ftT = (unsigned short*)(ws + 2772992);  // 4,194,304 B
  int useFtT = (ws_size >= (size_t)(2772992 + 4194304)) ? 1 : 0;

  k_pack_cw<<<256, 256, 0, stream>>>(conv_w, bpk);
  k_pack_cw2<<<32, 256, 0, stream>>>(conv_w, mlp_w, mlp_b, bpk2);
  if (useFtT) k_transpose_ft<<<512, 256, 0, stream>>>(feat, ftT);
  k_knn<<<512, 1024, 0, stream>>>(x, idx);
  k_main<<<4096, 256, 0, stream>>>(x, feat, ftT, useFtT, kern, bpk, bpk2,
                                   conv_b, idx, out);
  k_bnstats<<<64, 256, 0, stream>>>(out, gamma, beta, stats);
  k_bnapply<<<8192, 256, 0, stream>>>(out, stats);
}

// Round 8
// 177.974 us; speedup vs baseline: 1.5039x; 1.1354x over previous
//
#include <hip/hip_runtime.h>
#include <cfloat>
#include <math.h>

#define NB 8
#define NPT 4096
#define NC 64
#define KNN 20
#define KSZ 16
#define BPTS 8

typedef __attribute__((ext_vector_type(8))) short short8;
typedef __attribute__((ext_vector_type(4))) float f32x4;

// ---------- helpers ----------
__device__ __forceinline__ unsigned short f2bf(float f) {
  unsigned u = __float_as_uint(f);
  unsigned r = (u + 0x7fffu + ((u >> 16) & 1u)) >> 16;
  return (unsigned short)r;
}
__device__ __forceinline__ float bf2f(unsigned short h) {
  return __uint_as_float(((unsigned)h) << 16);
}

// ---------- K0a: conv_w lower half [64][0..1023] -> bpk B-frag bf16 (K=1024) ----------
__global__ void k_pack_cw(const float* __restrict__ cw, unsigned short* __restrict__ bp) {
  int t = blockIdx.x * 256 + threadIdx.x;  // 65536
  int j = t & 7, lane = (t >> 3) & 63, nt = (t >> 9) & 3, ks = t >> 11;  // ks 0..31
  int k = ks * 32 + ((lane >> 4) << 3) + j;   // 0..1023
  int o = nt * 16 + (lane & 15);
  bp[t] = f2bf(cw[o * 2048 + k]);
}

// ---------- K0a2: folded x_feats weights -> bpk2 B-frag bf16 (K=128) ----------
__global__ void k_pack_cw2(const float* __restrict__ cw, const float* __restrict__ mlp_w,
                           const float* __restrict__ mlp_b, unsigned short* __restrict__ bp2) {
  int t = blockIdx.x * 256 + threadIdx.x;  // 8192
  int jj = t & 7, lane = (t >> 3) & 63, nt = (t >> 9) & 3, ks2 = t >> 11;  // ks2 0..3
  int k = ks2 * 32 + ((lane >> 4) << 3) + jj;  // 0..127
  int s = k >> 3, j = k & 7;
  int o = nt * 16 + (lane & 15);
  float acc = 0.0f;
  for (int c = 0; c < 64; ++c) {
    float coef = (j < 7) ? mlp_w[c * 7 + j] : mlp_b[c];
    acc = fmaf(cw[o * 2048 + 1024 + c * 16 + s], coef, acc);
  }
  bp2[t] = f2bf(acc);
}

// ---------- K0b: feature [B][C][N] -> ftT [B][N][C] bf16 ----------
__global__ void k_transpose_ft(const float* __restrict__ f, unsigned short* __restrict__ ft) {
  __shared__ float tile[64][65];
  int b = blockIdx.x >> 6;
  int n0 = (blockIdx.x & 63) * 64;
  int lane = threadIdx.x & 63;
  int rr = threadIdx.x >> 6;  // 0..3
#pragma unroll
  for (int c0 = 0; c0 < 64; c0 += 4) {
    int c = c0 + rr;
    tile[c][lane] = f[(b * 64 + c) * 4096 + n0 + lane];
  }
  __syncthreads();
#pragma unroll
  for (int m0 = 0; m0 < 64; m0 += 4) {
    int nn = m0 + rr;
    ft[(b * 4096 + n0 + nn) * 64 + lane] = f2bf(tile[lane][nn]);
  }
}

// ---------- K1: KNN v4 (unchanged from R7) ----------
__device__ __noinline__ void knn_full(const float4* __restrict__ pts, int n, int lane,
                                      int g, int* __restrict__ idxOut) {
  const int M = 24;
  float4 qp = pts[n];
  float qx = qp.x, qy = qp.y, qz = qp.z;
  float v[M];
  int id[M];
#pragma unroll
  for (int r = 0; r < M; ++r) { v[r] = FLT_MAX; id[r] = 0x7fffffff; }
  for (int i = 0; i < 64; ++i) {
    int j = (i << 6) | lane;
    float4 p = pts[j];
    float dx = p.x - qx, dy = p.y - qy, dz = p.z - qz;
    float d2 = fmaf(dx, dx, fmaf(dy, dy, dz * dz));
    bool c[M];
#pragma unroll
    for (int r = 0; r < M; ++r) c[r] = d2 < v[r];
#pragma unroll
    for (int r = M - 1; r >= 1; --r) {
      v[r] = c[r - 1] ? v[r - 1] : (c[r] ? d2 : v[r]);
      id[r] = c[r - 1] ? id[r - 1] : (c[r] ? j : id[r]);
    }
    v[0] = c[0] ? d2 : v[0];
    id[0] = c[0] ? j : id[0];
  }
  unsigned long long key = ((unsigned long long)__float_as_uint(v[0]) << 32) | (unsigned)id[0];
  unsigned long long ext = ~0ull;
  for (int r = 0; r < 24; ++r) {
    unsigned long long k = key;
#pragma unroll
    for (int s = 1; s < 64; s <<= 1) {
      unsigned long long o = __shfl_xor(k, s, 64);
      k = (o < k) ? o : k;
    }
    if (lane == r) ext = k;
    if (key == k) {
#pragma unroll
      for (int q = 0; q < M - 1; ++q) { v[q] = v[q + 1]; id[q] = id[q + 1]; }
      v[M - 1] = FLT_MAX;
      id[M - 1] = 0x7fffffff;
      key = ((unsigned long long)__float_as_uint(v[0]) << 32) | (unsigned)id[0];
    }
  }
  int ei = (int)(unsigned)(ext & 0xffffffffu);
  bool al = lane < 24;
  double dv = -1.0;
  if (al) {
    float4 p = pts[ei];
    double dx = (double)p.x - (double)qx;
    double dy = (double)p.y - (double)qy;
    double dz = (double)p.z - (double)qz;
    dv = dx * dx + dy * dy + dz * dz;
  }
#pragma unroll
  for (int r = 0; r < 4; ++r) {
    double bd = al ? dv : -1.0;
    int bi = al ? ei : -1;
#pragma unroll
    for (int s = 1; s < 64; s <<= 1) {
      double od = __shfl_xor(bd, s, 64);
      int oi = __shfl_xor(bi, s, 64);
      if (od > bd || (od == bd && oi > bi)) { bd = od; bi = oi; }
    }
    if (al && ei == bi) al = false;
  }
  unsigned long long msk = __ballot(al && ei != n);
  if (al) {
    if (ei == n) {
      idxOut[g * 20] = n;
    } else {
      int pos = 1 + __popcll(msk & ((1ull << lane) - 1ull));
      idxOut[g * 20 + pos] = ei;
    }
  }
}

__launch_bounds__(1024, 2)
__global__ void k_knn(const float* __restrict__ x, int* __restrict__ idxOut) {
  __shared__ float4 pts[4096];  // 64KB: (x,y,z,xx)
  int b = blockIdx.x >> 6;      // 64 blocks/batch, 64 rows/block
  const float* xb = x + b * 3 * 4096;
  for (int i = threadIdx.x; i < 4096; i += 1024) {
    float px = xb[i], py = xb[4096 + i], pz = xb[8192 + i];
    pts[i] = make_float4(px, py, pz, fmaf(px, px, fmaf(py, py, pz * pz)));
  }
  __syncthreads();

  int lane = threadIdx.x & 63;
  int w = threadIdx.x >> 6;
  int nb = ((blockIdx.x & 63) << 6) + (w << 2);  // first of this wave's 4 rows
  int gb = b * 4096 + nb;

  float m2x[4], m2y[4], m2z[4];
#pragma unroll
  for (int r = 0; r < 4; ++r) {
    float4 q = pts[nb + r];
    m2x[r] = -2.0f * q.x;
    m2y[r] = -2.0f * q.y;
    m2z[r] = -2.0f * q.z;
  }

  // ---- pass 1: per-lane min for 4 rows ----
  float v[4];
#pragma unroll
  for (int r = 0; r < 4; ++r) v[r] = FLT_MAX;
#pragma unroll 2
  for (int i = 0; i < 64; ++i) {
    float4 p = pts[(i << 6) | lane];
#pragma unroll
    for (int r = 0; r < 4; ++r) {
      float d = fmaf(m2z[r], p.z, fmaf(m2y[r], p.y, fmaf(m2x[r], p.x, p.w)));
      v[r] = fminf(v[r], d);
    }
  }

  // ---- bitonic sort each row's 64 lane minima ----
#pragma unroll
  for (int k = 2; k <= 64; k <<= 1) {
#pragma unroll
    for (int j = k >> 1; j > 0; j >>= 1) {
      bool sel = ((lane & k) == 0) == ((lane & j) == 0);
#pragma unroll
      for (int r = 0; r < 4; ++r) {
        float o = __shfl_xor(v[r], j, 64);
        float mn = fminf(v[r], o), mx = fmaxf(v[r], o);
        v[r] = sel ? mn : mx;
      }
    }
  }
  float T[4];
#pragma unroll
  for (int r = 0; r < 4; ++r) T[r] = __shfl(v[r], 23, 64);

  // ---- pass 2: collect all d' <= T per row, compact via ds_permute ----
  int ei[4], base[4];
  bool ovf[4];
#pragma unroll
  for (int r = 0; r < 4; ++r) { ei[r] = -1; base[r] = 0; ovf[r] = false; }
#pragma unroll 2
  for (int i = 0; i < 64; ++i) {
    float4 p = pts[(i << 6) | lane];
#pragma unroll
    for (int r = 0; r < 4; ++r) {
      float d = fmaf(m2z[r], p.z, fmaf(m2y[r], p.y, fmaf(m2x[r], p.x, p.w)));
      bool pred = (d <= T[r]);
      unsigned long long mask = __ballot(pred);
      if (mask) {
        int cnt = __popcll(mask);
        if (base[r] + cnt > 63) {
          ovf[r] = true;
        } else {
          int dst = pred ? (base[r] + __popcll(mask & ((1ull << lane) - 1ull))) : 63;
          int got = __builtin_amdgcn_ds_permute(dst << 2, (i << 6) | lane);
          bool recv = (lane >= base[r]) && (lane < base[r] + cnt);
          ei[r] = recv ? got : ei[r];
        }
        base[r] += cnt;
      }
    }
  }

  // ---- per-row exact f64 lex rank-by-count + write ----
#pragma unroll
  for (int r = 0; r < 4; ++r) {
    int n = nb + r, g = gb + r;
    bool ok = !ovf[r];
    if (ok) {
      float4 qp = pts[n];
      bool act = lane < base[r];
      int e = ei[r];
      double dm = 1e300;
      if (act) {
        float4 p = pts[e];
        double dx = (double)p.x - (double)qp.x;
        double dy = (double)p.y - (double)qp.y;
        double dz = (double)p.z - (double)qp.z;
        dm = dx * dx + dy * dy + dz * dz;
      }
      int rank = 0;
      for (int r2 = 0; r2 < base[r]; ++r2) {
        double dr = __shfl(dm, r2, 64);
        int ir = __shfl(e, r2, 64);
        bool less = (dr < dm) || (dr == dm && ir < e);
        rank += less ? 1 : 0;
      }
      bool keep = act && (rank < 20);
      bool isSelf = keep && (e == n);
      unsigned long long smask = __ballot(isSelf);
      ok = (smask != 0ull);
      if (ok) {
        if (isSelf) idxOut[g * 20] = n;
        unsigned long long msk = __ballot(keep && !isSelf);
        if (keep && !isSelf) {
          int pos = 1 + __popcll(msk & ((1ull << lane) - 1ull));
          idxOut[g * 20 + pos] = e;
        }
      }
    }
    if (!ok) knn_full(pts, n, lane, g, idxOut);
  }
}

// ---------- K2: fused features + aw(bf16 B-frag) + MFMA agg + MFMA conv ----------
// 8 points/block, 256 threads (4 waves), 33KB LDS -> 4 blocks/CU.
// LDS map (manual offsets in one array; agg first so conv A-frag overreads
// rows 8..15 stay inside the 33KB block):
#define AGG_OFF 0            // bf16 agg[8][1024], 16KB; reused as f32 red
#define AWB_OFF 16384        // bf16 awB[8][512]  B-frag (32k x 16s per pt), 8KB
#define FPA_OFF 24576        // bf16 fpA[16][128] F' A-tile, 4KB
#define F7S_OFF 28672        // float4 f7s[8][20], 2560B
#define QL_OFF  31232        // float4 qL[8], 128B
#define IDX_OFF 31360        // int idxL[8][20], 640B
#define SMEM_SZ 33792        // 33KB total (>= 32KB so A-frag row 15 reads are in-bounds)

__launch_bounds__(256, 4)
__global__ void k_main(const float* __restrict__ x, const float* __restrict__ feat,
                       const unsigned short* __restrict__ ftT, int useFtT,
                       const float* __restrict__ kern,
                       const unsigned short* __restrict__ bpk,
                       const unsigned short* __restrict__ bpk2,
                       const float* __restrict__ conv_b, const int* __restrict__ idxIn,
                       float* __restrict__ out) {
  __shared__ __align__(16) unsigned char smem[SMEM_SZ];
  unsigned short* agg = (unsigned short*)(smem + AGG_OFF);
  unsigned short* awB = (unsigned short*)(smem + AWB_OFF);
  float4* f7s = (float4*)(smem + F7S_OFF);
  float4* qL = (float4*)(smem + QL_OFF);
  int* idxL = (int*)(smem + IDX_OFF);

  int t = threadIdx.x;
  int lane = t & 63;
  int w = t >> 6;
  // XCD swizzle: batch = blockIdx&7 pins each batch's ftT slice in one XCD L2.
  int b = blockIdx.x & 7;
  int n0 = (blockIdx.x >> 3) * BPTS;
  int g0 = b * 4096 + n0;
  const float* xb = x + b * 3 * 4096;

  // ---- step 0: geometry (8 pts x 20 nbrs) ----
  {
    int pt = t >> 5, slot = t & 31;
    int n = n0 + pt;
    float qx = xb[n], qy = xb[4096 + n], qz = xb[8192 + n];
    if (slot < 20) {
      int kk = idxIn[(g0 + pt) * 20 + slot];
      idxL[pt * 20 + slot] = kk;
      float rx = xb[kk] - qx, ry = xb[4096 + kk] - qy, rz = xb[8192 + kk] - qz;
      float ds = sqrtf(rx * rx + ry * ry + rz * rz);
      f7s[pt * 20 + slot] = make_float4(rx, ry, rz, ds);
    } else if (slot == 20) {
      qL[pt] = make_float4(qx, qy, qz, 0.0f);
    }
  }
  __syncthreads();

  // ---- step 1: aw chain -> awB bf16 B-frag + F' build (128 thr: (pt,s)) ----
  if (t < 128) {
    int pt = t >> 4, s = t & 15;
    float kx = kern[s], ky = kern[16 + s], kz = kern[32 + s];
    float wv[20];
#pragma unroll
    for (int k = 0; k < 20; ++k) {
      float4 f = f7s[pt * 20 + k];
      float dot = f.x * kx + f.y * ky + f.z * kz;
      if (s == 0 && k == 0) dot += 1.0f;
      wv[k] = dot > 0.0f ? dot : 0.0f;
    }
    float sum = 0.0f;
#pragma unroll
    for (int k = 0; k < 20; ++k) sum += wv[k];
    float inv1 = 1.0f / (sum + 1e-6f);
    float sum2 = 0.0f;
#pragma unroll
    for (int k = 0; k < 20; ++k) {
      float u = wv[k] * inv1;
      sum2 += u * u;
    }
    float inv2 = 1.0f / (sum2 + 1e-6f);
    float colsum = 0.0f;
    float F0 = 0.0f, F1 = 0.0f, F2 = 0.0f, F3 = 0.0f;
    unsigned short* awp = awB + pt * 512;
#pragma unroll
    for (int k = 0; k < 20; ++k) {
      float u = wv[k] * inv1;
      u = u * u * inv2;
      u = (u > 0.1f) ? u : 0.0f;
      // B-frag position: lane=(k>>3)*16+s, j=k&7
      awp[(((k >> 3) * 16 + s) << 3) + (k & 7)] = f2bf(u);
      colsum += u;
      float4 f = f7s[pt * 20 + k];
      F0 = fmaf(f.x, u, F0);
      F1 = fmaf(f.y, u, F1);
      F2 = fmaf(f.z, u, F2);
      F3 = fmaf(f.w, u, F3);
    }
#pragma unroll
    for (int k = 20; k < 32; ++k)
      awp[(((k >> 3) * 16 + s) << 3) + (k & 7)] = 0;
    float4 q = qL[pt];
    __align__(16) unsigned short tmp[8];
    tmp[0] = f2bf(q.x * colsum);
    tmp[1] = f2bf(q.y * colsum);
    tmp[2] = f2bf(q.z * colsum);
    tmp[3] = f2bf(F0);
    tmp[4] = f2bf(F1);
    tmp[5] = f2bf(F2);
    tmp[6] = f2bf(F3);
    tmp[7] = f2bf(colsum);
    *(uint4*)(smem + FPA_OFF + pt * 256 + ((s ^ (pt & 7)) << 4)) = *(uint4*)tmp;
  }
  __syncthreads();

  // ---- agg via MFMA: per pt, [64c x 32k(pad)] x [32k x 16s]; wave w does pts {2w,2w+1} ----
  {
    int r15 = lane & 15, chunk = lane >> 4;
#pragma unroll
    for (int half = 0; half < 2; ++half) {
      int pt = (w << 1) + half;
      // 8 neighbor indices for this lane's k-chunk (k = chunk*8+j), -1 => zero pad
      int nofs[8];
#pragma unroll
      for (int j = 0; j < 8; ++j) {
        int k = (chunk << 3) + j;
        nofs[j] = (k < 20) ? ((b * 4096 + idxL[pt * 20 + k]) << 6) : -1;
      }
      short8 bfrag = *(const short8*)(awB + pt * 512 + (lane << 3));
      f32x4 accA[4];
#pragma unroll
      for (int ct = 0; ct < 4; ++ct) accA[ct] = (f32x4){0.f, 0.f, 0.f, 0.f};
#pragma unroll
      for (int ct = 0; ct < 4; ++ct) {
        int c = (ct << 4) + r15;
        union { short8 v; unsigned short u[8]; } af;
#pragma unroll
        for (int j = 0; j < 8; ++j) {
          unsigned short val = 0;
          if (nofs[j] >= 0) {
            if (useFtT) val = ftT[nofs[j] + c];
            else val = f2bf(feat[(b * 64 + c) * 4096 + (nofs[j] >> 6) - b * 4096]);
          }
          af.u[j] = val;
        }
        accA[ct] = __builtin_amdgcn_mfma_f32_16x16x32_bf16(af.v, bfrag, accA[ct], 0, 0, 0);
      }
      // write C -> agg bf16, swizzled for conv A-frag reads
      // C: row c' = ct*16 + chunk*4 + q, col s = r15; k-index = c'*16 + s
      char* rb = (char*)(smem + AGG_OFF) + pt * 2048;
      int sw = (pt & 7) << 4;
#pragma unroll
      for (int ct = 0; ct < 4; ++ct)
#pragma unroll
        for (int q = 0; q < 4; ++q) {
          int kidx = (((ct << 4) + (chunk << 2) + q) << 4) + r15;
          *(unsigned short*)(rb + ((kidx << 1) ^ sw)) = f2bf(accA[ct][q]);
        }
    }
  }
  __syncthreads();

  // ---- conv GEMM: K=1024 (agg) + K=128 (F') ----
  f32x4 acc[4];
#pragma unroll
  for (int nt = 0; nt < 4; ++nt) acc[nt] = (f32x4){0.f, 0.f, 0.f, 0.f};
  {
    int r = lane & 15;
    const char* rowbase = (const char*)(smem + AGG_OFF) + r * 2048;
#pragma unroll
    for (int ks = 0; ks < 8; ++ks) {
      int ksl = w * 8 + ks;
      int off = (ksl * 64 + ((lane >> 4) << 4)) ^ ((r & 7) << 4);
      short8 af = *(const short8*)(rowbase + off);
#pragma unroll
      for (int nt = 0; nt < 4; ++nt) {
        short8 bf = *(const short8*)(bpk + (((ksl * 4 + nt) * 64 + lane) << 3));
        acc[nt] = __builtin_amdgcn_mfma_f32_16x16x32_bf16(af, bf, acc[nt], 0, 0, 0);
      }
    }
    {
      int chunk = (w << 2) + (lane >> 4);  // 0..15
      short8 af = *(const short8*)(smem + FPA_OFF + r * 256 + ((chunk ^ (r & 7)) << 4));
#pragma unroll
      for (int nt = 0; nt < 4; ++nt) {
        short8 bf = *(const short8*)(bpk2 + ((((w << 2) + nt) * 64 + lane) << 3));
        acc[nt] = __builtin_amdgcn_mfma_f32_16x16x32_bf16(af, bf, acc[nt], 0, 0, 0);
      }
    }
  }
  __syncthreads();  // before reusing agg as red

  // ---- cross-wave reduce ----
  float* red = (float*)(smem + AGG_OFF);  // 8KB of 16KB
  {
#pragma unroll
    for (int nt = 0; nt < 4; ++nt)
#pragma unroll
      for (int r = 0; r < 4; ++r) {
        int row = ((lane >> 4) << 2) + r;  // 0..15; only 0..7 valid
        if (row < 8) {
          int o = nt * 16 + (lane & 15);
          red[(w * 8 + row) * 64 + (o ^ ((row & 7) << 2))] = acc[nt][r];
        }
      }
  }
  __syncthreads();
#pragma unroll
  for (int rep = 0; rep < 2; ++rep) {
    int u = rep * 256 + t;
    int pt = u & 7, o = u >> 3;
    float s = conv_b[o];
#pragma unroll
    for (int w2 = 0; w2 < 4; ++w2) s += red[(w2 * 8 + pt) * 64 + (o ^ ((pt & 7) << 2))];
    out[(b * 64 + o) * 4096 + n0 + pt] = s;
  }
}

// ---------- K3a: BN stats stage 1 (512 blocks: one (batch,channel) slab) ----------
__global__ void k_bnstats1(const float* __restrict__ out, double* __restrict__ partial) {
  __shared__ double rs[256], rq[256];
  int o = blockIdx.x & 63, b = blockIdx.x >> 6;
  const float* p = out + (b * 64 + o) * 4096;
  double s = 0.0, q = 0.0;
  for (int i = threadIdx.x; i < 4096; i += 256) {
    double v = (double)p[i];
    s += v;
    q += v * v;
  }
  rs[threadIdx.x] = s;
  rq[threadIdx.x] = q;
  __syncthreads();
  for (int st = 128; st > 0; st >>= 1) {
    if ((int)threadIdx.x < st) {
      rs[threadIdx.x] += rs[threadIdx.x + st];
      rq[threadIdx.x] += rq[threadIdx.x + st];
    }
    __syncthreads();
  }
  if (threadIdx.x == 0) {
    partial[(o * 8 + b) * 2] = rs[0];
    partial[(o * 8 + b) * 2 + 1] = rq[0];
  }
}

// ---------- K3b: BN stats stage 2 (fixed-order combine; 1 block, 64 thr) ----------
__global__ void k_bnstats2(const double* __restrict__ partial, const float* __restrict__ gamma,
                           const float* __restrict__ beta, float* __restrict__ stats) {
  int o = threadIdx.x;
  double s = 0.0, q = 0.0;
#pragma unroll
  for (int b = 0; b < 8; ++b) {
    s += partial[(o * 8 + b) * 2];
    q += partial[(o * 8 + b) * 2 + 1];
  }
  double mean = s / 32768.0;
  double var = q / 32768.0 - mean * mean;
  double inv = 1.0 / sqrt(var + 1e-5);
  double sc = (double)gamma[o] * inv;
  stats[o * 2] = (float)sc;
  stats[o * 2 + 1] = (float)((double)beta[o] - mean * sc);
}

// ---------- K3c: BN apply (float4) ----------
__global__ void k_bnapply(float* __restrict__ out, const float* __restrict__ stats) {
  int i4 = blockIdx.x * 256 + threadIdx.x;  // 524288 float4s
  int o = (i4 >> 10) & 63;
  float sc = stats[o * 2], sh = stats[o * 2 + 1];
  float4 v = ((const float4*)out)[i4];
  v.x = fmaf(v.x, sc, sh);
  v.y = fmaf(v.y, sc, sh);
  v.z = fmaf(v.z, sc, sh);
  v.w = fmaf(v.w, sc, sh);
  ((float4*)out)[i4] = v;
}

extern "C" void kernel_launch(void* const* d_in, const int* in_sizes, int n_in,
                              void* d_out, int out_size, void* d_ws, size_t ws_size,
                              hipStream_t stream) {
  const float* x = (const float*)d_in[0];
  const float* feat = (const float*)d_in[1];
  const float* kern = (const float*)d_in[2];
  const float* mlp_w = (const float*)d_in[3];
  const float* mlp_b = (const float*)d_in[4];
  const float* conv_w = (const float*)d_in[5];
  const float* conv_b = (const float*)d_in[6];
  const float* gamma = (const float*)d_in[7];
  const float* beta = (const float*)d_in[8];
  float* out = (float*)d_out;
  char* ws = (char*)d_ws;

  // workspace layout
  int* idx = (int*)ws;                                    // 0 .. 2,621,440
  double* partial = (double*)(ws + 2621440);              // 8,192 B
  float* stats = (float*)(ws + 2629632);                  // 512 B (pad to 4KB)
  unsigned short* bpk = (unsigned short*)(ws + 2633728);  // 131,072 B (K=1024)
  unsigned short* bpk2 = (unsigned short*)(ws + 2764800); // 16,384 B  (K=128)
  unsigned short* ftT = (unsigned short*)(ws + 2781184);  // 4,194,304 B
  int useFtT = (ws_size >= (size_t)(2781184 + 4194304)) ? 1 : 0;

  k_pack_cw<<<256, 256, 0, stream>>>(conv_w, bpk);
  k_pack_cw2<<<32, 256, 0, stream>>>(conv_w, mlp_w, mlp_b, bpk2);
  if (useFtT) k_transpose_ft<<<512, 256, 0, stream>>>(feat, ftT);
  k_knn<<<512, 1024, 0, stream>>>(x, idx);
  k_main<<<4096, 256, 0, stream>>>(x, feat, ftT, useFtT, kern, bpk, bpk2,
                                   conv_b, idx, out);
  k_bnstats1<<<512, 256, 0, stream>>>(out, partial);
  k_bnstats2<<<1, 64, 0, stream>>>(partial, gamma, beta, stats);
  k_bnapply<<<2048, 256, 0, stream>>>(out, stats);
}